// Round 1
// baseline (28.592 us; speedup 1.0000x reference)
//
#include <hip/hip_runtime.h>

// Problem constants (from reference): BS=2048, P=32, C=14
constexpr int NB = 2048;   // batch
constexpr int NP = 32;     // spatial P
constexpr int NC = 14;     // channels
constexpr int ELEMS_PER_B = NP * NP * NC;  // 14336 floats per batch slice

// Block: 448 threads = 7 waves. tid = 7*r + c2 ; c2 in [0,7) -> channels (2c2, 2c2+1),
// r in [0,64). Per iteration `it` (16 total) thread reads float2 at flat offset
// it*896 + 2*tid, which equals pos*14 + ch with pos = it*64 + r, ch = 2*c2.
// => fully coalesced contiguous 448-thread x 8B reads.
__global__ __launch_bounds__(448) void loss_main(
    const float* __restrict__ y_pred,
    const float* __restrict__ eta,
    const float* __restrict__ p_in,
    const float* __restrict__ bbox,
    float* __restrict__ partial)
{
    const int b   = blockIdx.x;
    const int tid = threadIdx.x;
    const int c2  = tid % 7;
    const int r   = tid / 7;      // 0..63
    const int j   = r & 31;       // column index: CONSTANT per thread
    const int rhi = r >> 5;       // 0 or 1

    __shared__ int   win[NC][4];        // x0, y0, x1, y1 (int-truncated window)
    __shared__ float redAll[64][NC];
    __shared__ float red1[64][NC];
    __shared__ float red3[64][NC];
    __shared__ float lossArr[NC];

    if (tid < NC) {
        const float* bb = bbox + ((size_t)b * NC + tid) * 4;
        int x0 = (int)(bb[0] * (float)NP);   // truncation toward zero, matches astype(int32)
        int y0 = (int)(bb[1] * (float)NP);
        int w  = (int)(bb[2] * (float)NP);
        int h  = (int)(bb[3] * (float)NP);
        win[tid][0] = x0;
        win[tid][1] = y0;
        win[tid][2] = x0 + w;
        win[tid][3] = y0 + h;
    }
    __syncthreads();

    const int ca = 2 * c2, cb = ca + 1;
    const int xa0 = win[ca][0], ya0 = win[ca][1], xa1 = win[ca][2], ya1 = win[ca][3];
    const int xb0 = win[cb][0], yb0 = win[cb][1], xb1 = win[cb][2], yb1 = win[cb][3];
    const bool colA = (j >= xa0) && (j < xa1);
    const bool colB = (j >= xb0) && (j < xb1);

    float allA = 1.f, p1A = 1.f, p3A = 1.f;
    float allB = 1.f, p1B = 1.f, p3B = 1.f;

    const float* base = y_pred + (size_t)b * ELEMS_PER_B;

    #pragma unroll
    for (int it = 0; it < 16; ++it) {
        const float2 v = *reinterpret_cast<const float2*>(base + it * 896 + 2 * tid);
        const int i = 2 * it + rhi;   // row index
        // channel A (v.x)
        {
            float yp0 = fminf(1.f, v.x);
            float t0  = fminf(1.f, 1.f - yp0);
            float yp  = fmaf(yp0, 0.02f, 0.98f);
            float t   = fmaf(t0,  0.02f, 0.98f);
            allA *= t;
            bool m = colA && (i >= ya0) && (i < ya1);
            p1A *= m ? yp : 1.f;
            p3A *= m ? t  : 1.f;
        }
        // channel B (v.y)
        {
            float yp0 = fminf(1.f, v.y);
            float t0  = fminf(1.f, 1.f - yp0);
            float yp  = fmaf(yp0, 0.02f, 0.98f);
            float t   = fmaf(t0,  0.02f, 0.98f);
            allB *= t;
            bool m = colB && (i >= yb0) && (i < yb1);
            p1B *= m ? yp : 1.f;
            p3B *= m ? t  : 1.f;
        }
    }

    redAll[r][ca] = allA;  redAll[r][cb] = allB;
    red1[r][ca]   = p1A;   red1[r][cb]   = p1B;
    red3[r][ca]   = p3A;   red3[r][cb]   = p3B;
    __syncthreads();

    // multiply-tree over the 64 row-partials per channel
    for (int s = 32; s >= 1; s >>= 1) {
        if (tid < s * NC) {
            int rr = tid / NC, cc = tid % NC;
            redAll[rr][cc] *= redAll[rr + s][cc];
            red1[rr][cc]   *= red1[rr + s][cc];
            red3[rr][cc]   *= red3[rr + s][cc];
        }
        __syncthreads();
    }

    if (tid < NC) {
        float Pall = redAll[0][tid];   // prod of tmp over all (i,j)
        float P1   = red1[0][tid];     // prod of yp inside bbox
        float P3   = red3[0][tid];     // prod of tmp inside bbox
        float pyx  = 1.f - Pall;                    // p_y_x
        float pyxb = P1 * Pall / P3 + 1e-10f;       // p_y_x_bbox
        float e  = eta[(size_t)b * NC + tid];
        float pp = p_in[(size_t)b * NC + tid];
        // log(1 - p_y_x) == log(Pall)
        float loss = -e * logf(pyxb)
                     - (1.f - e) * pp * logf(pyx)
                     - (1.f - e) * (1.f - pp) * logf(Pall);
        lossArr[tid] = loss;
    }
    __syncthreads();

    if (tid == 0) {
        float s = 0.f;
        #pragma unroll
        for (int c = 0; c < NC; ++c) s += lossArr[c];
        partial[b] = s;
    }
}

// Deterministic final reduction: fixed-order tree, overwrites d_out (no atomics).
__global__ __launch_bounds__(256) void reduce_partials(
    const float* __restrict__ partial, float* __restrict__ out)
{
    __shared__ float s[256];
    float acc = 0.f;
    for (int i = threadIdx.x; i < NB; i += 256) acc += partial[i];
    s[threadIdx.x] = acc;
    __syncthreads();
    for (int st = 128; st >= 1; st >>= 1) {
        if (threadIdx.x < st) s[threadIdx.x] += s[threadIdx.x + st];
        __syncthreads();
    }
    if (threadIdx.x == 0) out[0] = s[0] / (float)NB;
}

extern "C" void kernel_launch(void* const* d_in, const int* in_sizes, int n_in,
                              void* d_out, int out_size, void* d_ws, size_t ws_size,
                              hipStream_t stream)
{
    const float* y_pred = (const float*)d_in[0];
    const float* eta    = (const float*)d_in[1];
    const float* p_in   = (const float*)d_in[2];
    const float* bbox   = (const float*)d_in[3];
    float* partial = (float*)d_ws;          // 2048 floats = 8 KB scratch
    float* out     = (float*)d_out;

    loss_main<<<NB, 448, 0, stream>>>(y_pred, eta, p_in, bbox, partial);
    reduce_partials<<<1, 256, 0, stream>>>(partial, out);
}